// Round 2
// baseline (111.830 us; speedup 1.0000x reference)
//
#include <hip/hip_runtime.h>
#include <hip/hip_bf16.h>
#include <math.h>

#define B_     32
#define HID_   768
#define OUT5_  2304
#define HDIM_  512
#define NC_    65536
#define MAXG_  11
#define NL_    670091
#define TOPK_  10
#define CAND_  110   // TOPK_*MAXG_
#define NOUT_  3520  // B_*CAND_

__device__ __forceinline__ float gelu_exact(float x){
  return 0.5f * x * (1.0f + erff(x * 0.70710678118654752440f));
}

__device__ __forceinline__ unsigned long long packv(float x, int col){
  unsigned u = __float_as_uint(x);
  u = (u & 0x80000000u) ? ~u : (u | 0x80000000u);   // order-preserving float->uint
  return (((unsigned long long)u) << 16) | (unsigned long long)(65535 - col); // tie -> lower col wins
}

__device__ __forceinline__ float unpack_val(unsigned long long g){
  unsigned u = (unsigned)(g >> 16);
  unsigned bits = (u & 0x80000000u) ? (u & 0x7FFFFFFFu) : ~u;
  return __uint_as_float(bits);
}

__device__ __forceinline__ int unpack_col(unsigned long long g){
  return 65535 - (int)(g & 0xFFFFULL);
}

__device__ __forceinline__ unsigned long long block_max_u64(unsigned long long m,
                                                            unsigned long long* sm, int nwaves){
  #pragma unroll
  for (int off = 1; off < 64; off <<= 1){
    unsigned long long o = __shfl_xor(m, off);
    if (o > m) m = o;
  }
  const int tid = threadIdx.x;
  if ((tid & 63) == 0) sm[tid >> 6] = m;
  __syncthreads();
  unsigned long long g = sm[0];
  for (int w = 1; w < nwaves; ++w) if (sm[w] > g) g = sm[w];
  __syncthreads();   // safe to reuse sm next round
  return g;
}

// K1: partial sums for the two small GEMMs, deterministic k-chunk split (no atomics).
__global__ __launch_bounds__(256)
void mlp_partial(const float* __restrict__ hidf, const float* __restrict__ hidl5,
                 const float* __restrict__ W1, const float* __restrict__ Wext,
                 float* __restrict__ partial){
  const int jl  = threadIdx.x & 63;
  const int bq  = threadIdx.x >> 6;           // wave id: 8 batch rows each
  const int col = blockIdx.x * 64 + jl;
  const int chunk = blockIdx.y;
  const float* W; const float* X; int Kfull, k0;
  if (chunk < 4){ W = W1;   X = hidf;  Kfull = HID_;  k0 = chunk * 192; }
  else          { W = Wext; X = hidl5; Kfull = OUT5_; k0 = (chunk - 4) * 192; }
  const float* Wp = W + (size_t)k0 * HDIM_ + col;
  const float* Xp = X + (size_t)(bq * 8) * Kfull + k0;
  float acc[8] = {0,0,0,0,0,0,0,0};
  for (int k = 0; k < 192; ++k){
    float w = Wp[(size_t)k * HDIM_];
    #pragma unroll
    for (int i = 0; i < 8; ++i)
      acc[i] = fmaf(Xp[(size_t)i * Kfull + k], w, acc[i]);
  }
  float* outp = partial + (size_t)chunk * (B_ * HDIM_) + (size_t)(bq * 8) * HDIM_ + col;
  #pragma unroll
  for (int i = 0; i < 8; ++i) outp[(size_t)i * HDIM_] = acc[i];
}

// K2: reduce chunks + bias + exact GELU. Meta-h stored transposed [HDIM][B] for K3.
__global__ __launch_bounds__(256)
void act_kernel(const float* __restrict__ partial, const float* __restrict__ b1,
                const float* __restrict__ bext, float* __restrict__ hT,
                float* __restrict__ h_ext){
  const int t = blockIdx.x * 256 + threadIdx.x;  // 0..32767
  if (t < B_ * HDIM_){
    const int b = t >> 9, j = t & 511;
    float s = b1[j];
    #pragma unroll
    for (int c = 0; c < 4; ++c) s += partial[c * (B_ * HDIM_) + t];
    hT[j * B_ + b] = gelu_exact(s);
  } else {
    const int u = t - B_ * HDIM_;
    const int j = u & 511;
    float s = bext[j];
    #pragma unroll
    for (int c = 4; c < 16; ++c) s += partial[c * (B_ * HDIM_) + u];
    h_ext[u] = gelu_exact(s);
  }
}

// K3: meta_logits = hT^T @ W2 + b2.  512 blocks x 256 thr.
__global__ __launch_bounds__(256)
void meta_gemm(const float* __restrict__ hT, const float* __restrict__ W2,
               const float* __restrict__ b2, float* __restrict__ logits){
  const int lane = threadIdx.x & 63;
  const int bq   = threadIdx.x >> 6;
  const int col0 = blockIdx.x * 128 + lane * 2;
  const int sb8  = __builtin_amdgcn_readfirstlane(bq * 8);   // uniform -> scalar loads
  const float* __restrict__ hrow = hT + sb8;
  const float2* __restrict__ Wp = reinterpret_cast<const float2*>(W2) + (col0 >> 1);
  float acc[8][2];
  #pragma unroll
  for (int i = 0; i < 8; ++i){ acc[i][0] = 0.f; acc[i][1] = 0.f; }
  #pragma unroll 4
  for (int k = 0; k < HDIM_; ++k){
    float2 w  = Wp[(size_t)k * (NC_ / 2)];
    float4 h0 = *reinterpret_cast<const float4*>(hrow + (size_t)k * B_);
    float4 h1 = *reinterpret_cast<const float4*>(hrow + (size_t)k * B_ + 4);
    acc[0][0] = fmaf(h0.x, w.x, acc[0][0]); acc[0][1] = fmaf(h0.x, w.y, acc[0][1]);
    acc[1][0] = fmaf(h0.y, w.x, acc[1][0]); acc[1][1] = fmaf(h0.y, w.y, acc[1][1]);
    acc[2][0] = fmaf(h0.z, w.x, acc[2][0]); acc[2][1] = fmaf(h0.z, w.y, acc[2][1]);
    acc[3][0] = fmaf(h0.w, w.x, acc[3][0]); acc[3][1] = fmaf(h0.w, w.y, acc[3][1]);
    acc[4][0] = fmaf(h1.x, w.x, acc[4][0]); acc[4][1] = fmaf(h1.x, w.y, acc[4][1]);
    acc[5][0] = fmaf(h1.y, w.x, acc[5][0]); acc[5][1] = fmaf(h1.y, w.y, acc[5][1]);
    acc[6][0] = fmaf(h1.z, w.x, acc[6][0]); acc[6][1] = fmaf(h1.z, w.y, acc[6][1]);
    acc[7][0] = fmaf(h1.w, w.x, acc[7][0]); acc[7][1] = fmaf(h1.w, w.y, acc[7][1]);
  }
  const float2 bb = *reinterpret_cast<const float2*>(b2 + col0);
  #pragma unroll
  for (int i = 0; i < 8; ++i){
    float2 o; o.x = acc[i][0] + bb.x; o.y = acc[i][1] + bb.y;
    *reinterpret_cast<float2*>(logits + (size_t)(sb8 + i) * NC_ + col0) = o;
  }
}

// K4: per-(row, 8192-col segment) top-10.  grid 256 = 32 rows x 8 segments.
__global__ __launch_bounds__(256)
void topk_seg(const float* __restrict__ logits, float* __restrict__ segv,
              int* __restrict__ segi){
  __shared__ unsigned long long sm[4];
  const int b   = blockIdx.x >> 3;
  const int seg = blockIdx.x & 7;
  const int tid = threadIdx.x;
  const float* row = logits + (size_t)b * NC_ + seg * 8192;
  float v[10]; int ix[10];
  #pragma unroll
  for (int r = 0; r < 10; ++r){ v[r] = -INFINITY; ix[r] = -1; }
  for (int s = 0; s < 32; ++s){
    const int j = s * 256 + tid;
    const float x = row[j];
    if (x > v[9]){
      v[9] = x; ix[9] = seg * 8192 + j;
      #pragma unroll
      for (int p = 9; p > 0; --p){
        if (v[p] > v[p-1]){
          float tv = v[p]; v[p] = v[p-1]; v[p-1] = tv;
          int   ti = ix[p]; ix[p] = ix[p-1]; ix[p-1] = ti;
        }
      }
    }
  }
  for (int r = 0; r < 10; ++r){
    unsigned long long mp = (ix[0] >= 0) ? packv(v[0], ix[0]) : 0ULL;
    unsigned long long g  = block_max_u64(mp, sm, 4);
    if (mp == g && mp != 0ULL){
      #pragma unroll
      for (int q = 0; q < 9; ++q){ v[q] = v[q+1]; ix[q] = ix[q+1]; }
      v[9] = -INFINITY; ix[9] = -1;
    }
    if (tid == 0){
      segv[blockIdx.x * 10 + r] = unpack_val(g);
      segi[blockIdx.x * 10 + r] = unpack_col(g);
    }
  }
}

// K5: merge 8 segment top-10s -> global top-10 per row. grid 32 x 128 thr.
__global__ __launch_bounds__(128)
void topk_merge(const float* __restrict__ segv, const int* __restrict__ segi,
                int* __restrict__ tk_idx, float* __restrict__ tk_score){
  __shared__ unsigned long long sm[2];
  const int b   = blockIdx.x;
  const int tid = threadIdx.x;
  unsigned long long mp = 0ULL;
  if (tid < 80) mp = packv(segv[b * 80 + tid], segi[b * 80 + tid]);
  for (int r = 0; r < 10; ++r){
    unsigned long long g = block_max_u64(mp, sm, 2);
    if (mp == g && mp != 0ULL) mp = 0ULL;   // consumed
    if (tid == 0){
      tk_idx[b * TOPK_ + r]   = unpack_col(g);
      tk_score[b * TOPK_ + r] = 1.0f / (1.0f + expf(-unpack_val(g)));
    }
  }
}

// K6: candidate gather + dot + final outputs.
// d_out layout: [cands f32 x3520][cscores bf16 x3520][comb bf16 x3520]
// group_y dtype (int64 vs int32) auto-detected per wave: probe 64 odd 32-bit
// words; all-zero  =>  int64 layout (high halves). Misdetect prob ~ (1/670092)^64.
__global__ __launch_bounds__(256)
void cand_kernel(const int* __restrict__ gy, const float* __restrict__ embed,
                 const float* __restrict__ h_ext, const int* __restrict__ tk_idx,
                 const float* __restrict__ tk_score, float* __restrict__ out_f){
  const int wid  = threadIdx.x >> 6;
  const int lane = threadIdx.x & 63;
  const int gw   = blockIdx.x * 4 + wid;        // 0..3519
  const int b    = gw / CAND_;
  const int c    = gw - b * CAND_;
  const int t    = c / MAXG_;
  const int g    = c - t * MAXG_;

  const unsigned int* gyw = (const unsigned int*)gy;
  const unsigned int probe = gyw[2 * (size_t)(gw * 64 + lane) + 1]; // < 450560 words, in-bounds both layouts
  const bool is64 = (__ballot(probe != 0u) == 0ULL);

  const int idx  = tk_idx[b * TOPK_ + t];
  const size_t li = (size_t)idx * MAXG_ + g;
  const int cand = is64 ? (int)((const long long*)gy)[li] : gy[li];

  const float* erow = embed + (size_t)cand * HDIM_;
  const float* hrow = h_ext + (size_t)b * HDIM_;
  const float4 e0 = reinterpret_cast<const float4*>(erow)[lane];
  const float4 e1 = reinterpret_cast<const float4*>(erow)[lane + 64];
  const float4 h0 = reinterpret_cast<const float4*>(hrow)[lane];
  const float4 h1 = reinterpret_cast<const float4*>(hrow)[lane + 64];
  float s = e0.x*h0.x + e0.y*h0.y + e0.z*h0.z + e0.w*h0.w
          + e1.x*h1.x + e1.y*h1.y + e1.z*h1.z + e1.w*h1.w;
  #pragma unroll
  for (int off = 1; off < 64; off <<= 1) s += __shfl_xor(s, off);
  if (lane == 0){
    const float cs   = (s == 0.0f) ? 0.0f : 1.0f / (1.0f + expf(-s));  // logit==0 -> -inf -> sigmoid 0
    const float comb = cs * ((cand != NL_) ? tk_score[b * TOPK_ + t] : 0.0f);
    const int o = b * CAND_ + c;
    __hip_bfloat16* outs = (__hip_bfloat16*)(out_f + NOUT_);  // byte 14080
    __hip_bfloat16* outm = outs + NOUT_;                      // byte 21120
    out_f[o] = (float)cand;
    outs[o]  = __float2bfloat16(cs);
    outm[o]  = __float2bfloat16(comb);
  }
}

extern "C" void kernel_launch(void* const* d_in, const int* in_sizes, int n_in,
                              void* d_out, int out_size, void* d_ws, size_t ws_size,
                              hipStream_t stream){
  const float* hidf  = (const float*)d_in[0];
  const float* hidl5 = (const float*)d_in[1];
  const float* W1    = (const float*)d_in[2];
  const float* b1    = (const float*)d_in[3];
  const float* W2    = (const float*)d_in[4];
  const float* b2    = (const float*)d_in[5];
  const float* Wext  = (const float*)d_in[6];
  const float* bext  = (const float*)d_in[7];
  const float* embed = (const float*)d_in[8];
  const int*   gy    = (const int*)d_in[9];
  float* out_f = (float*)d_out;

  float* ws      = (float*)d_ws;
  float* logits  = ws;                          // [32][65536] f32 (8 MiB)
  float* partial = ws;                          // 16*16384 f32, aliased into logits (dead before meta_gemm)
  float* hT      = logits + (size_t)B_ * NC_;   // [512][32]
  float* h_ext   = hT + B_ * HDIM_;             // [32][512]
  float* segv    = h_ext + B_ * HDIM_;          // 2560
  int*   segi    = (int*)(segv + 2560);         // 2560
  float* tk_sc   = (float*)(segi + 2560);       // 320
  int*   tk_ix   = (int*)(tk_sc + 320);         // 320

  mlp_partial<<<dim3(8, 16), 256, 0, stream>>>(hidf, hidl5, W1, Wext, partial);
  act_kernel <<<128, 256, 0, stream>>>(partial, b1, bext, hT, h_ext);
  meta_gemm  <<<NC_ / 128, 256, 0, stream>>>(hT, W2, b2, logits);
  topk_seg   <<<B_ * 8, 256, 0, stream>>>(logits, segv, segi);
  topk_merge <<<B_, 128, 0, stream>>>(segv, segi, tk_ix, tk_sc);
  cand_kernel<<<NOUT_ / 4, 256, 0, stream>>>(gy, embed, h_ext, tk_ix, tk_sc, out_f);
}